// Round 18
// baseline (1198.307 us; speedup 1.0000x reference)
//
#include <hip/hip_runtime.h>
#include <math.h>

namespace {

constexpr int Bn = 8192;
constexpr int Dn = 508;
constexpr int Hn = 256;
constexpr int NSTEPS = 8;
constexpr int Kp = 512;  // D padded to 512 (zero-padded on the WEIGHT side)
constexpr float DT = 1.f / NSTEPS;
constexpr float DT6 = DT / 6.f;

typedef __attribute__((ext_vector_type(8))) short short8v;
typedef __attribute__((ext_vector_type(4))) float f32x4;

__device__ __forceinline__ short f2b(float f) {
  union { float f; unsigned u; } v; v.f = f;
  unsigned r = v.u + 0x7fffu + ((v.u >> 16) & 1u);
  return (short)(r >> 16);
}
__device__ __forceinline__ float b2f(short s) {
  union { unsigned u; float f; } v;
  v.u = ((unsigned)(unsigned short)s) << 16;
  return v.f;
}
__device__ __forceinline__ unsigned pk2(short lo, short hi) {
  return ((unsigned)(unsigned short)lo) | (((unsigned)(unsigned short)hi) << 16);
}
__device__ __forceinline__ float upk_lo(unsigned p) {
  union { unsigned u; float f; } v; v.u = p << 16; return v.f;
}
__device__ __forceinline__ float upk_hi(unsigned p) {
  union { unsigned u; float f; } v; v.u = p & 0xffff0000u; return v.f;
}
__device__ __forceinline__ float ftanh(float x) {
  x = fminf(fmaxf(x, -12.f), 12.f);
  const float e = __expf(2.f * x);
  return __fdividef(e - 1.f, e + 1.f);
}

// ---------------- shared 64x64-block MFMA core for SETUP kernels (validated r2)
template <int KT>
__device__ __forceinline__ void gemm_bb(const short* __restrict__ A, int lda,
                                        const short* __restrict__ Bt, int ldb,
                                        int row0, int col0, int lane,
                                        f32x4 acc[2][2]) {
  const int r = lane & 15, g = lane >> 4;
  const short* a0p = A + (size_t)(row0 + r) * lda + g * 8;
  const short* a1p = A + (size_t)(row0 + 16 + r) * lda + g * 8;
  const short* b0p = Bt + (size_t)(col0 + r) * ldb + g * 8;
  const short* b1p = Bt + (size_t)(col0 + 16 + r) * ldb + g * 8;
#pragma unroll
  for (int kt = 0; kt < KT; ++kt) {
    const short8v a0 = *(const short8v*)(a0p + kt * 32);
    const short8v a1 = *(const short8v*)(a1p + kt * 32);
    const short8v b0 = *(const short8v*)(b0p + kt * 32);
    const short8v b1 = *(const short8v*)(b1p + kt * 32);
    acc[0][0] = __builtin_amdgcn_mfma_f32_16x16x32_bf16(a0, b0, acc[0][0], 0, 0, 0);
    acc[0][1] = __builtin_amdgcn_mfma_f32_16x16x32_bf16(a0, b1, acc[0][1], 0, 0, 0);
    acc[1][0] = __builtin_amdgcn_mfma_f32_16x16x32_bf16(a1, b0, acc[1][0], 0, 0, 0);
    acc[1][1] = __builtin_amdgcn_mfma_f32_16x16x32_bf16(a1, b1, acc[1][1], 0, 0, 0);
  }
}

#define GEMM_PROLOGUE()                                     \
  const int tid = threadIdx.x, wid = tid >> 6, lane = tid & 63; \
  const int row0 = blockIdx.y * 64 + (wid >> 1) * 32;       \
  const int col0 = blockIdx.x * 64 + (wid & 1) * 32;        \
  const int rq = (lane >> 4) * 4, cc = lane & 15;           \
  const f32x4 z4 = {0.f, 0.f, 0.f, 0.f};                    \
  f32x4 acc[2][2] = {{z4, z4}, {z4, z4}};

// ---------------- setup kernels (r12-validated) ----------------

__global__ __launch_bounds__(256) void k_cast_bf(const float* __restrict__ src, int R,
                                                 int C, short* __restrict__ dst, int ldd) {
  const int total = R * ldd;
  for (int idx = blockIdx.x * 256 + threadIdx.x; idx < total; idx += gridDim.x * 256) {
    const int r = idx / ldd, c = idx - r * ldd;
    dst[idx] = (c < C) ? f2b(src[(size_t)r * C + c]) : (short)0;
  }
}

__global__ __launch_bounds__(256) void k_transpose_bf(const float* __restrict__ src, int K,
                                                      int N, short* __restrict__ dst,
                                                      int Nd, int ldd) {
  const int total = Nd * ldd;
  for (int idx = blockIdx.x * 256 + threadIdx.x; idx < total; idx += gridDim.x * 256) {
    const int n = idx / ldd, k = idx - n * ldd;
    dst[idx] = (k < K && n < N) ? f2b(src[(size_t)k * N + n]) : (short)0;
  }
}

__global__ __launch_bounds__(256) void k_c0(const float* __restrict__ w0,
                                            const float* __restrict__ b2,
                                            float* __restrict__ c0) {
  const int n = threadIdx.x;
  float s = 0.f;
#pragma unroll 8
  for (int d = 0; d < Dn; ++d) s += b2[d] * w0[(size_t)d * Hn + n];
  c0[n] = s;
}

__global__ __launch_bounds__(256) void k_w20t(const short* __restrict__ w0T,
                                              const short* __restrict__ w2b,
                                              short* __restrict__ w20T) {
  GEMM_PROLOGUE();
  gemm_bb<16>(w0T, Kp, w2b, Kp, row0, col0, lane, acc);
#pragma unroll
  for (int i = 0; i < 2; ++i)
#pragma unroll
    for (int j = 0; j < 2; ++j)
#pragma unroll
      for (int q = 0; q < 4; ++q)
        w20T[(size_t)(row0 + i * 16 + rq + q) * Hn + col0 + j * 16 + cc] =
            f2b(acc[i][j][q]);
}

// z = f32(x)@w0T + cond*w0c  (f32-A GEMM, folds the x->bf16 cast)
__global__ __launch_bounds__(256) void k_ginitx(const float* __restrict__ Af,
                                                const short* __restrict__ Bt,
                                                const float* __restrict__ cond,
                                                const float* __restrict__ w0c,
                                                float* __restrict__ zout) {
  GEMM_PROLOGUE();
  const int g = lane >> 4;
  const float* a0r = Af + (size_t)(row0 + cc) * Dn;
  const float* a1r = Af + (size_t)(row0 + 16 + cc) * Dn;
  const short* b0p = Bt + (size_t)(col0 + cc) * Kp + g * 8;
  const short* b1p = Bt + (size_t)(col0 + 16 + cc) * Kp + g * 8;
#pragma unroll
  for (int kt = 0; kt < 16; ++kt) {
    const int k = kt * 32 + g * 8;
    short8v a0v, a1v;
#pragma unroll
    for (int h = 0; h < 2; ++h) {
      const int k4 = k + h * 4;
      float4 fa = make_float4(0.f, 0.f, 0.f, 0.f);
      float4 fb = make_float4(0.f, 0.f, 0.f, 0.f);
      if (k4 < Dn) {
        fa = *(const float4*)(a0r + k4);
        fb = *(const float4*)(a1r + k4);
      }
      a0v[h * 4 + 0] = f2b(fa.x); a0v[h * 4 + 1] = f2b(fa.y);
      a0v[h * 4 + 2] = f2b(fa.z); a0v[h * 4 + 3] = f2b(fa.w);
      a1v[h * 4 + 0] = f2b(fb.x); a1v[h * 4 + 1] = f2b(fb.y);
      a1v[h * 4 + 2] = f2b(fb.z); a1v[h * 4 + 3] = f2b(fb.w);
    }
    const short8v b0v = *(const short8v*)(b0p + kt * 32);
    const short8v b1v = *(const short8v*)(b1p + kt * 32);
    acc[0][0] = __builtin_amdgcn_mfma_f32_16x16x32_bf16(a0v, b0v, acc[0][0], 0, 0, 0);
    acc[0][1] = __builtin_amdgcn_mfma_f32_16x16x32_bf16(a0v, b1v, acc[0][1], 0, 0, 0);
    acc[1][0] = __builtin_amdgcn_mfma_f32_16x16x32_bf16(a1v, b0v, acc[1][0], 0, 0, 0);
    acc[1][1] = __builtin_amdgcn_mfma_f32_16x16x32_bf16(a1v, b1v, acc[1][1], 0, 0, 0);
  }
#pragma unroll
  for (int i = 0; i < 2; ++i)
#pragma unroll
    for (int j = 0; j < 2; ++j)
#pragma unroll
      for (int q = 0; q < 4; ++q) {
        const int row = row0 + i * 16 + rq + q;
        const int col = col0 + j * 16 + cc;
        zout[(size_t)row * Hn + col] = acc[i][j][q] + cond[row] * w0c[col];
      }
}

// u = bf16(eps@w0T), g2 = bf16(eps@w2b): one eps read, two B-streams.
__global__ __launch_bounds__(256) void k_giniteps(const float* __restrict__ Af,
                                                  const short* __restrict__ BtU,
                                                  const short* __restrict__ BtG,
                                                  short* __restrict__ uout,
                                                  short* __restrict__ gout) {
  GEMM_PROLOGUE();
  f32x4 acc2[2][2] = {{z4, z4}, {z4, z4}};
  const int g = lane >> 4;
  const float* a0r = Af + (size_t)(row0 + cc) * Dn;
  const float* a1r = Af + (size_t)(row0 + 16 + cc) * Dn;
  const short* u0p = BtU + (size_t)(col0 + cc) * Kp + g * 8;
  const short* u1p = BtU + (size_t)(col0 + 16 + cc) * Kp + g * 8;
  const short* g0p = BtG + (size_t)(col0 + cc) * Kp + g * 8;
  const short* g1p = BtG + (size_t)(col0 + 16 + cc) * Kp + g * 8;
#pragma unroll
  for (int kt = 0; kt < 16; ++kt) {
    const int k = kt * 32 + g * 8;
    short8v a0v, a1v;
#pragma unroll
    for (int h = 0; h < 2; ++h) {
      const int k4 = k + h * 4;
      float4 fa = make_float4(0.f, 0.f, 0.f, 0.f);
      float4 fb = make_float4(0.f, 0.f, 0.f, 0.f);
      if (k4 < Dn) {
        fa = *(const float4*)(a0r + k4);
        fb = *(const float4*)(a1r + k4);
      }
      a0v[h * 4 + 0] = f2b(fa.x); a0v[h * 4 + 1] = f2b(fa.y);
      a0v[h * 4 + 2] = f2b(fa.z); a0v[h * 4 + 3] = f2b(fa.w);
      a1v[h * 4 + 0] = f2b(fb.x); a1v[h * 4 + 1] = f2b(fb.y);
      a1v[h * 4 + 2] = f2b(fb.z); a1v[h * 4 + 3] = f2b(fb.w);
    }
    const short8v bu0 = *(const short8v*)(u0p + kt * 32);
    const short8v bu1 = *(const short8v*)(u1p + kt * 32);
    const short8v bg0 = *(const short8v*)(g0p + kt * 32);
    const short8v bg1 = *(const short8v*)(g1p + kt * 32);
    acc[0][0] = __builtin_amdgcn_mfma_f32_16x16x32_bf16(a0v, bu0, acc[0][0], 0, 0, 0);
    acc[0][1] = __builtin_amdgcn_mfma_f32_16x16x32_bf16(a0v, bu1, acc[0][1], 0, 0, 0);
    acc[1][0] = __builtin_amdgcn_mfma_f32_16x16x32_bf16(a1v, bu0, acc[1][0], 0, 0, 0);
    acc[1][1] = __builtin_amdgcn_mfma_f32_16x16x32_bf16(a1v, bu1, acc[1][1], 0, 0, 0);
    acc2[0][0] = __builtin_amdgcn_mfma_f32_16x16x32_bf16(a0v, bg0, acc2[0][0], 0, 0, 0);
    acc2[0][1] = __builtin_amdgcn_mfma_f32_16x16x32_bf16(a0v, bg1, acc2[0][1], 0, 0, 0);
    acc2[1][0] = __builtin_amdgcn_mfma_f32_16x16x32_bf16(a1v, bg0, acc2[1][0], 0, 0, 0);
    acc2[1][1] = __builtin_amdgcn_mfma_f32_16x16x32_bf16(a1v, bg1, acc2[1][1], 0, 0, 0);
  }
#pragma unroll
  for (int i = 0; i < 2; ++i)
#pragma unroll
    for (int j = 0; j < 2; ++j)
#pragma unroll
      for (int q = 0; q < 4; ++q) {
        const int row = row0 + i * 16 + rq + q;
        const int col = col0 + j * 16 + cc;
        uout[(size_t)row * Hn + col] = f2b(acc[i][j][q]);
        gout[(size_t)row * Hn + col] = f2b(acc2[i][j][q]);
      }
}

// Re-pack a [N][256] bf16 B^T matrix into MFMA fragment order:
// dst[ ((c16*8 + ks)*64 + lane)*8 + j ] = src[ (c16*16 + (lane&15))*256
//                                             + ks*32 + (lane>>4)*8 + j ]
__global__ __launch_bounds__(256) void k_fragpack(const short* __restrict__ src,
                                                  short* __restrict__ dst, int total) {
  for (int idx = blockIdx.x * 256 + threadIdx.x; idx < total; idx += gridDim.x * 256) {
    const int j = idx & 7;
    const int l = (idx >> 3) & 63;
    const int ks = (idx >> 9) & 7;
    const int c16 = idx >> 12;
    dst[idx] = src[(size_t)(c16 * 16 + (l & 15)) * 256 + ks * 32 + (l >> 4) * 8 + j];
  }
}

// ---------------- the fused ODE kernel ----------------
// r18 = r14 chassis + BARRIER AMORTIZATION: 32 rows/block (rb in {0,1})
// at the same wg=512 / 8-wave / 32-col-strip geometry. Same 2 barriers
// per eval now cover 2x rows -> barriers per row halved; phase C gains 4
// interleaved MFMA chains. B' keeps r10's exact 4-chain inner structure,
// run once per rb (b-frags re-read per rb from the L2-hot stream). To fit
// the 128-VGPR cap with doubled state, hs moves to LDS f32 [32][258].
// Register audit: persistent z/kzp/kza 48 + u/g2 16 + tr 8 + consts 8
// ~= 80; transient 32 -> peak ~112 < 128. LDS ~82 KB -> 1 block/CU
// (which is all this toolchain ever grants). grid = 256.

__device__ __forceinline__ int swz(int row, int col) {
  return (row * 256 + col) ^ ((row & 7) << 3);
}

constexpr int HP = 258;  // padded f32 row stride for hsum LDS

__global__ __launch_bounds__(512) void k_mega(
    const float* __restrict__ zg, const short* __restrict__ u_g,
    const short* __restrict__ g2_g, const short* __restrict__ w1P,
    const short* __restrict__ w20P, const short* __restrict__ w2P,
    const float* __restrict__ b0, const float* __restrict__ w0t,
    const float* __restrict__ b1, const float* __restrict__ c0,
    const float* __restrict__ b2, const float* __restrict__ x,
    float* __restrict__ yout, float* __restrict__ ldout) {
  __shared__ short As[64 * 256];   // stacked [h0 rows 0-31; m0 rows 32-63]
  __shared__ short h1s[32 * 256];
  __shared__ float hsum[32 * HP];
  __shared__ float red[32][8];

  const int tid = threadIdx.x;
  const int w = tid >> 6, lane = tid & 63;
  const int cc = lane & 15, g = lane >> 4, rq = g * 4;
  const int r0 = blockIdx.x * 32;
  const int cb = w * 32;  // wave's 32-col strip

  // per-lane column constants (nt in {0,1})
  float b0c[2], w0tc[2], b1c[2], c0c[2];
#pragma unroll
  for (int nt = 0; nt < 2; ++nt) {
    const int col = cb + nt * 16 + cc;
    b0c[nt] = b0[col];
    w0tc[nt] = w0t[col];
    b1c[nt] = b1[col];
    c0c[nt] = c0[col];
  }

  // fragment-packed weight bases for this wave (c16 = 2w, 2w+1):
  const short* w1base = w1P + (size_t)(2 * w) * 4096 + lane * 8;
  const short* w20base = w20P + (size_t)(2 * w) * 4096 + lane * 8;

  // element (rb,nt,q): gbase + (rb*16+q)*Hn + nt*16
  const size_t gbase = (size_t)(r0 + rq) * Hn + cb + cc;

  // persistent per-thread register state (hs in LDS)
  float z_[2][2][4], kzp[2][2][4], kza[2][2][4], tr_[2][4];
  unsigned u_pk[2][2][2], g2_pk[2][2][2];  // [rb][nt][qpair]
#pragma unroll
  for (int rb = 0; rb < 2; ++rb)
#pragma unroll
    for (int nt = 0; nt < 2; ++nt) {
      const size_t i0 = gbase + (size_t)(rb * 16) * Hn + nt * 16;
#pragma unroll
      for (int q = 0; q < 4; ++q) {
        z_[rb][nt][q] = zg[i0 + (size_t)q * Hn];
        kzp[rb][nt][q] = 0.f;
      }
      u_pk[rb][nt][0] = pk2(u_g[i0], u_g[i0 + Hn]);
      u_pk[rb][nt][1] = pk2(u_g[i0 + 2 * Hn], u_g[i0 + 3 * Hn]);
      g2_pk[rb][nt][0] = pk2(g2_g[i0], g2_g[i0 + Hn]);
      g2_pk[rb][nt][1] = pk2(g2_g[i0 + 2 * Hn], g2_g[i0 + 3 * Hn]);
    }
#pragma unroll
  for (int rb = 0; rb < 2; ++rb)
#pragma unroll
    for (int q = 0; q < 4; ++q) tr_[rb][q] = 0.f;

  for (int i = tid; i < 32 * HP; i += 512) hsum[i] = 0.f;
  // the A->B' barrier of eval 0 orders these inits vs the first hsum RMW

  const f32x4 zero4 = {0.f, 0.f, 0.f, 0.f};

#pragma unroll 1
  for (int e = 0; e < 4 * NSTEPS; ++e) {
    const int j = e & 3, s = e >> 2;
    const float oj = (j == 0) ? 0.f : ((j == 3) ? 1.f : 0.5f);
    const float aj = (j == 0) ? 0.f : ((j == 3) ? DT : 0.5f * DT);
    const float mj = (j == 1 || j == 2) ? 2.f : 1.f;
    const float tval = ((float)s + oj) * DT;

    // ---- A: h0 = tanh(z + aj*kzp + b0 + t*w0t); m0 = (1-h0^2)*u -> stacked As
#pragma unroll
    for (int rb = 0; rb < 2; ++rb)
#pragma unroll
      for (int nt = 0; nt < 2; ++nt)
#pragma unroll
        for (int q = 0; q < 4; ++q) {
          const int row = rb * 16 + rq + q;
          const int colh = cb + nt * 16 + cc;
          const float pre =
              z_[rb][nt][q] + aj * kzp[rb][nt][q] + b0c[nt] + tval * w0tc[nt];
          const float h = ftanh(pre);
          const float uq = (q & 1) ? upk_hi(u_pk[rb][nt][q >> 1])
                                   : upk_lo(u_pk[rb][nt][q >> 1]);
          As[swz(row, colh)] = f2b(h);
          As[swz(32 + row, colh)] = f2b((1.f - h * h) * uq);
        }
    __syncthreads();

    // ---- B': [h0;m0] @ w1, per-rb pass of the r10 4-chain core
#pragma unroll
    for (int rb = 0; rb < 2; ++rb) {
      f32x4 acc[2][2] = {{zero4, zero4}, {zero4, zero4}};  // [h0/m0][nt]
#pragma unroll
      for (int ks = 0; ks < 8; ++ks) {
        const short8v b0v = *(const short8v*)(w1base + ks * 512);
        const short8v b1v = *(const short8v*)(w1base + 4096 + ks * 512);
        const short8v a0 = *(const short8v*)(As + swz(rb * 16 + cc, g * 8 + ks * 32));
        const short8v a1 =
            *(const short8v*)(As + swz(32 + rb * 16 + cc, g * 8 + ks * 32));
        acc[0][0] = __builtin_amdgcn_mfma_f32_16x16x32_bf16(a0, b0v, acc[0][0], 0, 0, 0);
        acc[0][1] = __builtin_amdgcn_mfma_f32_16x16x32_bf16(a0, b1v, acc[0][1], 0, 0, 0);
        acc[1][0] = __builtin_amdgcn_mfma_f32_16x16x32_bf16(a1, b0v, acc[1][0], 0, 0, 0);
        acc[1][1] = __builtin_amdgcn_mfma_f32_16x16x32_bf16(a1, b1v, acc[1][1], 0, 0, 0);
      }
#pragma unroll
      for (int nt = 0; nt < 2; ++nt)
#pragma unroll
        for (int q = 0; q < 4; ++q) {
          const float v = ftanh(acc[0][nt][q] + b1c[nt]);
          const float g2q = (q & 1) ? upk_hi(g2_pk[rb][nt][q >> 1])
                                    : upk_lo(g2_pk[rb][nt][q >> 1]);
          tr_[rb][q] += (DT6 * mj) * g2q * (1.f - v * v) * acc[1][nt][q];
          const int row = rb * 16 + rq + q;
          const int colh = cb + nt * 16 + cc;
          h1s[swz(row, colh)] = f2b(v);
          hsum[row * HP + colh] += mj * v;
        }
    }
    __syncthreads();

    // ---- C: kz = h1@w20 + c0 ; RK4 state update (4 chains: [rb][nt])
    {
      f32x4 acc2[2][2] = {{zero4, zero4}, {zero4, zero4}};
#pragma unroll
      for (int ks = 0; ks < 8; ++ks) {
        const short8v b0v = *(const short8v*)(w20base + ks * 512);
        const short8v b1v = *(const short8v*)(w20base + 4096 + ks * 512);
        const short8v a0 = *(const short8v*)(h1s + swz(cc, g * 8 + ks * 32));
        const short8v a1 = *(const short8v*)(h1s + swz(16 + cc, g * 8 + ks * 32));
        acc2[0][0] = __builtin_amdgcn_mfma_f32_16x16x32_bf16(a0, b0v, acc2[0][0], 0, 0, 0);
        acc2[0][1] = __builtin_amdgcn_mfma_f32_16x16x32_bf16(a0, b1v, acc2[0][1], 0, 0, 0);
        acc2[1][0] = __builtin_amdgcn_mfma_f32_16x16x32_bf16(a1, b0v, acc2[1][0], 0, 0, 0);
        acc2[1][1] = __builtin_amdgcn_mfma_f32_16x16x32_bf16(a1, b1v, acc2[1][1], 0, 0, 0);
      }
#pragma unroll
      for (int rb = 0; rb < 2; ++rb)
#pragma unroll
        for (int nt = 0; nt < 2; ++nt)
#pragma unroll
          for (int q = 0; q < 4; ++q) {
            const float kzv = acc2[rb][nt][q] + c0c[nt];
            if (j == 0) {
              kza[rb][nt][q] = kzv;
              kzp[rb][nt][q] = kzv;
            } else if (j < 3) {
              kza[rb][nt][q] += mj * kzv;
              kzp[rb][nt][q] = kzv;
            } else {
              z_[rb][nt][q] += DT6 * (kza[rb][nt][q] + kzv);
            }
          }
    }
    // no barrier: next A writes As only (disjoint from h1s); the A->B'
    // barrier orders h1s reuse across waves.
  }

  // ---- final: y = x + DT6 * HS@w2 + b2  (sum of dt*b2 over 8 steps = b2)
#pragma unroll
  for (int rb = 0; rb < 2; ++rb)
#pragma unroll
    for (int nt = 0; nt < 2; ++nt)
#pragma unroll
      for (int q = 0; q < 4; ++q) {
        const int row = rb * 16 + rq + q;
        const int colh = cb + nt * 16 + cc;
        As[swz(row, colh)] = f2b(hsum[row * HP + colh]);
      }
  __syncthreads();
  // 512 output cols over 8 waves -> wave covers 64 cols (c16 = 4w + nt),
  // per-rb pass keeps the register peak low.
#pragma unroll 1
  for (int rb = 0; rb < 2; ++rb) {
    const short* w2base = w2P + (size_t)(4 * w) * 4096 + lane * 8;
    f32x4 facc[4] = {zero4, zero4, zero4, zero4};
#pragma unroll
    for (int ks = 0; ks < 8; ++ks) {
      const short8v a = *(const short8v*)(As + swz(rb * 16 + cc, g * 8 + ks * 32));
#pragma unroll
      for (int nt = 0; nt < 4; ++nt) {
        const short8v bv = *(const short8v*)(w2base + nt * 4096 + ks * 512);
        facc[nt] = __builtin_amdgcn_mfma_f32_16x16x32_bf16(a, bv, facc[nt], 0, 0, 0);
      }
    }
#pragma unroll
    for (int nt = 0; nt < 4; ++nt) {
      const int colo = w * 64 + nt * 16 + cc;
      if (colo < Dn) {
        const float b2c = b2[colo];
#pragma unroll
        for (int q = 0; q < 4; ++q) {
          const size_t ix = (size_t)(r0 + rb * 16 + rq + q) * Dn + colo;
          yout[ix] = x[ix] + DT6 * facc[nt][q] + b2c;
        }
      }
    }
  }

  // ---- trace reduction: over the 16 cc-lanes, then over 8 waves
#pragma unroll
  for (int rb = 0; rb < 2; ++rb)
#pragma unroll
    for (int q = 0; q < 4; ++q) {
      float v = tr_[rb][q];
      v += __shfl_xor(v, 1);
      v += __shfl_xor(v, 2);
      v += __shfl_xor(v, 4);
      v += __shfl_xor(v, 8);
      if (cc == 0) red[rb * 16 + rq + q][w] = v;
    }
  __syncthreads();
  if (tid < 32) {
    float t = 0.f;
#pragma unroll
    for (int ww = 0; ww < 8; ++ww) t += red[tid][ww];
    ldout[r0 + tid] = t;
  }
}

}  // namespace

extern "C" void kernel_launch(void* const* d_in, const int* in_sizes, int n_in,
                              void* d_out, int out_size, void* d_ws, size_t ws_size,
                              hipStream_t stream) {
  const float* x = (const float*)d_in[0];
  const float* cond = (const float*)d_in[1];
  const float* eps = (const float*)d_in[2];
  const float* w0 = (const float*)d_in[3];
  const float* b0 = (const float*)d_in[4];
  const float* w1 = (const float*)d_in[5];
  const float* b1 = (const float*)d_in[6];
  const float* w2 = (const float*)d_in[7];
  const float* b2 = (const float*)d_in[8];
  const float* w0c = w0 + (size_t)508 * Hn;  // cond row
  const float* w0t = w0 + (size_t)509 * Hn;  // time row

  const size_t BD = (size_t)Bn * Dn, BH = (size_t)Bn * Hn;
  char* p = (char*)d_ws;
  auto alloc_f = [&](size_t n) { float* r = (float*)p; p += n * 4; return r; };
  auto alloc_s = [&](size_t n) { short* r = (short*)p; p += ((n * 2 + 15) & ~15ull); return r; };

  float* zg = alloc_f(BH);
  float* c0 = alloc_f(256);
  short* u_g = alloc_s(BH);
  short* g2_g = alloc_s(BH);
  short* w0T = alloc_s(256 * 512);
  short* w1T = alloc_s(256 * 256);
  short* w2b = alloc_s(256 * 512);
  short* w2T = alloc_s(512 * 256);
  short* w20T = alloc_s(256 * 256);
  short* w1P = alloc_s(256 * 256);   // fragment-packed
  short* w20P = alloc_s(256 * 256);  // fragment-packed
  short* w2P = alloc_s(512 * 256);   // fragment-packed

  float* yout = (float*)d_out;        // [B, D]
  float* ldout = (float*)d_out + BD;  // [B]

  const dim3 blk(256);
  const dim3 gH(Hn / 64, Bn / 64);  // (4,128)
  const dim3 gW(4, 4);

  // ---- setup (weights + z/u/g2 precompute; x/eps casts folded into GEMMs)
  k_cast_bf<<<512, blk, 0, stream>>>(w2, Hn, Dn, w2b, Kp);
  k_transpose_bf<<<256, blk, 0, stream>>>(w1, Hn, Hn, w1T, Hn, Hn);
  k_transpose_bf<<<512, blk, 0, stream>>>(w0, Dn, Hn, w0T, Hn, Kp);
  k_transpose_bf<<<512, blk, 0, stream>>>(w2, Hn, Dn, w2T, Kp, Hn);
  k_c0<<<1, blk, 0, stream>>>(w0, b2, c0);
  k_w20t<<<gW, blk, 0, stream>>>(w0T, w2b, w20T);
  k_ginitx<<<gH, blk, 0, stream>>>(x, w0T, cond, w0c, zg);
  k_giniteps<<<gH, blk, 0, stream>>>(eps, w0T, w2b, u_g, g2_g);
  k_fragpack<<<256, blk, 0, stream>>>(w1T, w1P, 256 * 256);
  k_fragpack<<<256, blk, 0, stream>>>(w20T, w20P, 256 * 256);
  k_fragpack<<<512, blk, 0, stream>>>(w2T, w2P, 512 * 256);

  // ---- the whole ODE in one kernel ----
  k_mega<<<dim3(Bn / 32), dim3(512), 0, stream>>>(zg, u_g, g2_g, w1P, w20P,
                                                  w2P, b0, w0t, b1, c0, b2, x,
                                                  yout, ldout);
}

// Round 19
// 306.183 us; speedup vs baseline: 3.9137x; 3.9137x over previous
//
#include <hip/hip_runtime.h>
#include <math.h>

namespace {

constexpr int Bn = 8192;
constexpr int Dn = 508;
constexpr int Hn = 256;
constexpr int NSTEPS = 8;
constexpr int Kp = 512;  // D padded to 512 (zero-padded on the WEIGHT side)
constexpr float DT = 1.f / NSTEPS;
constexpr float DT6 = DT / 6.f;

typedef __attribute__((ext_vector_type(8))) short short8v;
typedef __attribute__((ext_vector_type(4))) float f32x4;

__device__ __forceinline__ short f2b(float f) {
  union { float f; unsigned u; } v; v.f = f;
  unsigned r = v.u + 0x7fffu + ((v.u >> 16) & 1u);
  return (short)(r >> 16);
}
__device__ __forceinline__ float b2f(short s) {
  union { unsigned u; float f; } v;
  v.u = ((unsigned)(unsigned short)s) << 16;
  return v.f;
}
__device__ __forceinline__ unsigned pk2(short lo, short hi) {
  return ((unsigned)(unsigned short)lo) | (((unsigned)(unsigned short)hi) << 16);
}
__device__ __forceinline__ float upk_lo(unsigned p) {
  union { unsigned u; float f; } v; v.u = p << 16; return v.f;
}
__device__ __forceinline__ float upk_hi(unsigned p) {
  union { unsigned u; float f; } v; v.u = p & 0xffff0000u; return v.f;
}
__device__ __forceinline__ float ftanh(float x) {
  x = fminf(fmaxf(x, -12.f), 12.f);
  const float e = __expf(2.f * x);
  return __fdividef(e - 1.f, e + 1.f);
}

// ---------------- shared 64x64-block MFMA core for SETUP kernels (validated r2)
template <int KT>
__device__ __forceinline__ void gemm_bb(const short* __restrict__ A, int lda,
                                        const short* __restrict__ Bt, int ldb,
                                        int row0, int col0, int lane,
                                        f32x4 acc[2][2]) {
  const int r = lane & 15, g = lane >> 4;
  const short* a0p = A + (size_t)(row0 + r) * lda + g * 8;
  const short* a1p = A + (size_t)(row0 + 16 + r) * lda + g * 8;
  const short* b0p = Bt + (size_t)(col0 + r) * ldb + g * 8;
  const short* b1p = Bt + (size_t)(col0 + 16 + r) * ldb + g * 8;
#pragma unroll
  for (int kt = 0; kt < KT; ++kt) {
    const short8v a0 = *(const short8v*)(a0p + kt * 32);
    const short8v a1 = *(const short8v*)(a1p + kt * 32);
    const short8v b0 = *(const short8v*)(b0p + kt * 32);
    const short8v b1 = *(const short8v*)(b1p + kt * 32);
    acc[0][0] = __builtin_amdgcn_mfma_f32_16x16x32_bf16(a0, b0, acc[0][0], 0, 0, 0);
    acc[0][1] = __builtin_amdgcn_mfma_f32_16x16x32_bf16(a0, b1, acc[0][1], 0, 0, 0);
    acc[1][0] = __builtin_amdgcn_mfma_f32_16x16x32_bf16(a1, b0, acc[1][0], 0, 0, 0);
    acc[1][1] = __builtin_amdgcn_mfma_f32_16x16x32_bf16(a1, b1, acc[1][1], 0, 0, 0);
  }
}

#define GEMM_PROLOGUE()                                     \
  const int tid = threadIdx.x, wid = tid >> 6, lane = tid & 63; \
  const int row0 = blockIdx.y * 64 + (wid >> 1) * 32;       \
  const int col0 = blockIdx.x * 64 + (wid & 1) * 32;        \
  const int rq = (lane >> 4) * 4, cc = lane & 15;           \
  const f32x4 z4 = {0.f, 0.f, 0.f, 0.f};                    \
  f32x4 acc[2][2] = {{z4, z4}, {z4, z4}};

// ---------------- setup kernels (r12-validated) ----------------

__global__ __launch_bounds__(256) void k_cast_bf(const float* __restrict__ src, int R,
                                                 int C, short* __restrict__ dst, int ldd) {
  const int total = R * ldd;
  for (int idx = blockIdx.x * 256 + threadIdx.x; idx < total; idx += gridDim.x * 256) {
    const int r = idx / ldd, c = idx - r * ldd;
    dst[idx] = (c < C) ? f2b(src[(size_t)r * C + c]) : (short)0;
  }
}

__global__ __launch_bounds__(256) void k_transpose_bf(const float* __restrict__ src, int K,
                                                      int N, short* __restrict__ dst,
                                                      int Nd, int ldd) {
  const int total = Nd * ldd;
  for (int idx = blockIdx.x * 256 + threadIdx.x; idx < total; idx += gridDim.x * 256) {
    const int n = idx / ldd, k = idx - n * ldd;
    dst[idx] = (k < K && n < N) ? f2b(src[(size_t)k * N + n]) : (short)0;
  }
}

__global__ __launch_bounds__(256) void k_c0(const float* __restrict__ w0,
                                            const float* __restrict__ b2,
                                            float* __restrict__ c0) {
  const int n = threadIdx.x;
  float s = 0.f;
#pragma unroll 8
  for (int d = 0; d < Dn; ++d) s += b2[d] * w0[(size_t)d * Hn + n];
  c0[n] = s;
}

__global__ __launch_bounds__(256) void k_w20t(const short* __restrict__ w0T,
                                              const short* __restrict__ w2b,
                                              short* __restrict__ w20T) {
  GEMM_PROLOGUE();
  gemm_bb<16>(w0T, Kp, w2b, Kp, row0, col0, lane, acc);
#pragma unroll
  for (int i = 0; i < 2; ++i)
#pragma unroll
    for (int j = 0; j < 2; ++j)
#pragma unroll
      for (int q = 0; q < 4; ++q)
        w20T[(size_t)(row0 + i * 16 + rq + q) * Hn + col0 + j * 16 + cc] =
            f2b(acc[i][j][q]);
}

// z = f32(x)@w0T + cond*w0c  (f32-A GEMM, folds the x->bf16 cast)
__global__ __launch_bounds__(256) void k_ginitx(const float* __restrict__ Af,
                                                const short* __restrict__ Bt,
                                                const float* __restrict__ cond,
                                                const float* __restrict__ w0c,
                                                float* __restrict__ zout) {
  GEMM_PROLOGUE();
  const int g = lane >> 4;
  const float* a0r = Af + (size_t)(row0 + cc) * Dn;
  const float* a1r = Af + (size_t)(row0 + 16 + cc) * Dn;
  const short* b0p = Bt + (size_t)(col0 + cc) * Kp + g * 8;
  const short* b1p = Bt + (size_t)(col0 + 16 + cc) * Kp + g * 8;
#pragma unroll
  for (int kt = 0; kt < 16; ++kt) {
    const int k = kt * 32 + g * 8;
    short8v a0v, a1v;
#pragma unroll
    for (int h = 0; h < 2; ++h) {
      const int k4 = k + h * 4;
      float4 fa = make_float4(0.f, 0.f, 0.f, 0.f);
      float4 fb = make_float4(0.f, 0.f, 0.f, 0.f);
      if (k4 < Dn) {
        fa = *(const float4*)(a0r + k4);
        fb = *(const float4*)(a1r + k4);
      }
      a0v[h * 4 + 0] = f2b(fa.x); a0v[h * 4 + 1] = f2b(fa.y);
      a0v[h * 4 + 2] = f2b(fa.z); a0v[h * 4 + 3] = f2b(fa.w);
      a1v[h * 4 + 0] = f2b(fb.x); a1v[h * 4 + 1] = f2b(fb.y);
      a1v[h * 4 + 2] = f2b(fb.z); a1v[h * 4 + 3] = f2b(fb.w);
    }
    const short8v b0v = *(const short8v*)(b0p + kt * 32);
    const short8v b1v = *(const short8v*)(b1p + kt * 32);
    acc[0][0] = __builtin_amdgcn_mfma_f32_16x16x32_bf16(a0v, b0v, acc[0][0], 0, 0, 0);
    acc[0][1] = __builtin_amdgcn_mfma_f32_16x16x32_bf16(a0v, b1v, acc[0][1], 0, 0, 0);
    acc[1][0] = __builtin_amdgcn_mfma_f32_16x16x32_bf16(a1v, b0v, acc[1][0], 0, 0, 0);
    acc[1][1] = __builtin_amdgcn_mfma_f32_16x16x32_bf16(a1v, b1v, acc[1][1], 0, 0, 0);
  }
#pragma unroll
  for (int i = 0; i < 2; ++i)
#pragma unroll
    for (int j = 0; j < 2; ++j)
#pragma unroll
      for (int q = 0; q < 4; ++q) {
        const int row = row0 + i * 16 + rq + q;
        const int col = col0 + j * 16 + cc;
        zout[(size_t)row * Hn + col] = acc[i][j][q] + cond[row] * w0c[col];
      }
}

// u = bf16(eps@w0T), g2 = bf16(eps@w2b): one eps read, two B-streams.
__global__ __launch_bounds__(256) void k_giniteps(const float* __restrict__ Af,
                                                  const short* __restrict__ BtU,
                                                  const short* __restrict__ BtG,
                                                  short* __restrict__ uout,
                                                  short* __restrict__ gout) {
  GEMM_PROLOGUE();
  f32x4 acc2[2][2] = {{z4, z4}, {z4, z4}};
  const int g = lane >> 4;
  const float* a0r = Af + (size_t)(row0 + cc) * Dn;
  const float* a1r = Af + (size_t)(row0 + 16 + cc) * Dn;
  const short* u0p = BtU + (size_t)(col0 + cc) * Kp + g * 8;
  const short* u1p = BtU + (size_t)(col0 + 16 + cc) * Kp + g * 8;
  const short* g0p = BtG + (size_t)(col0 + cc) * Kp + g * 8;
  const short* g1p = BtG + (size_t)(col0 + 16 + cc) * Kp + g * 8;
#pragma unroll
  for (int kt = 0; kt < 16; ++kt) {
    const int k = kt * 32 + g * 8;
    short8v a0v, a1v;
#pragma unroll
    for (int h = 0; h < 2; ++h) {
      const int k4 = k + h * 4;
      float4 fa = make_float4(0.f, 0.f, 0.f, 0.f);
      float4 fb = make_float4(0.f, 0.f, 0.f, 0.f);
      if (k4 < Dn) {
        fa = *(const float4*)(a0r + k4);
        fb = *(const float4*)(a1r + k4);
      }
      a0v[h * 4 + 0] = f2b(fa.x); a0v[h * 4 + 1] = f2b(fa.y);
      a0v[h * 4 + 2] = f2b(fa.z); a0v[h * 4 + 3] = f2b(fa.w);
      a1v[h * 4 + 0] = f2b(fb.x); a1v[h * 4 + 1] = f2b(fb.y);
      a1v[h * 4 + 2] = f2b(fb.z); a1v[h * 4 + 3] = f2b(fb.w);
    }
    const short8v bu0 = *(const short8v*)(u0p + kt * 32);
    const short8v bu1 = *(const short8v*)(u1p + kt * 32);
    const short8v bg0 = *(const short8v*)(g0p + kt * 32);
    const short8v bg1 = *(const short8v*)(g1p + kt * 32);
    acc[0][0] = __builtin_amdgcn_mfma_f32_16x16x32_bf16(a0v, bu0, acc[0][0], 0, 0, 0);
    acc[0][1] = __builtin_amdgcn_mfma_f32_16x16x32_bf16(a0v, bu1, acc[0][1], 0, 0, 0);
    acc[1][0] = __builtin_amdgcn_mfma_f32_16x16x32_bf16(a1v, bu0, acc[1][0], 0, 0, 0);
    acc[1][1] = __builtin_amdgcn_mfma_f32_16x16x32_bf16(a1v, bu1, acc[1][1], 0, 0, 0);
    acc2[0][0] = __builtin_amdgcn_mfma_f32_16x16x32_bf16(a0v, bg0, acc2[0][0], 0, 0, 0);
    acc2[0][1] = __builtin_amdgcn_mfma_f32_16x16x32_bf16(a0v, bg1, acc2[0][1], 0, 0, 0);
    acc2[1][0] = __builtin_amdgcn_mfma_f32_16x16x32_bf16(a1v, bg0, acc2[1][0], 0, 0, 0);
    acc2[1][1] = __builtin_amdgcn_mfma_f32_16x16x32_bf16(a1v, bg1, acc2[1][1], 0, 0, 0);
  }
#pragma unroll
  for (int i = 0; i < 2; ++i)
#pragma unroll
    for (int j = 0; j < 2; ++j)
#pragma unroll
      for (int q = 0; q < 4; ++q) {
        const int row = row0 + i * 16 + rq + q;
        const int col = col0 + j * 16 + cc;
        uout[(size_t)row * Hn + col] = f2b(acc[i][j][q]);
        gout[(size_t)row * Hn + col] = f2b(acc2[i][j][q]);
      }
}

// Re-pack a [N][256] bf16 B^T matrix into MFMA fragment order:
// dst[ ((c16*8 + ks)*64 + lane)*8 + j ] = src[ (c16*16 + (lane&15))*256
//                                             + ks*32 + (lane>>4)*8 + j ]
__global__ __launch_bounds__(256) void k_fragpack(const short* __restrict__ src,
                                                  short* __restrict__ dst, int total) {
  for (int idx = blockIdx.x * 256 + threadIdx.x; idx < total; idx += gridDim.x * 256) {
    const int j = idx & 7;
    const int l = (idx >> 3) & 63;
    const int ks = (idx >> 9) & 7;
    const int c16 = idx >> 12;
    dst[idx] = src[(size_t)(c16 * 16 + (l & 15)) * 256 + ks * 32 + (l >> 4) * 8 + j];
  }
}

// ---------------- the fused ODE kernel (r10/r14/r17 VERBATIM — measured
// optimum: 240 us k_mega / 306 us total, VGPR 128 spill-free, FETCH 24 MB,
// occ 22%. Eight structural deviations (occupancy attributes r5/r8/r11,
// reg diet r13/r15, wg=1024 r12, wg=256 dual-block r16, barrier
// amortization r18) all regressed; this configuration is converged on
// this toolchain.) ----------------
// wg=512 (8 waves), 16 batch rows/block, grid=512. Wave w owns cols
// [w*32, w*32+32). ALL state + u/g2 in registers. Only recurring global
// traffic: fragment-packed weight stream (L2-hot).

__device__ __forceinline__ int swz(int row, int col) {
  return (row * 256 + col) ^ ((row & 7) << 3);
}

__global__ __launch_bounds__(512) void k_mega(
    const float* __restrict__ zg, const short* __restrict__ u_g,
    const short* __restrict__ g2_g, const short* __restrict__ w1P,
    const short* __restrict__ w20P, const short* __restrict__ w2P,
    const float* __restrict__ b0, const float* __restrict__ w0t,
    const float* __restrict__ b1, const float* __restrict__ c0,
    const float* __restrict__ b2, const float* __restrict__ x,
    float* __restrict__ yout, float* __restrict__ ldout) {
  __shared__ short As[32 * 256];   // stacked [h0 rows 0-15; m0 rows 16-31]
  __shared__ short h1s[16 * 256];
  __shared__ float red[16][8];

  const int tid = threadIdx.x;
  const int w = tid >> 6, lane = tid & 63;
  const int cc = lane & 15, g = lane >> 4, rq = g * 4;
  const int r0 = blockIdx.x * 16;
  const int cb = w * 32;  // wave's 32-col strip

  // per-lane column constants (nt in {0,1})
  float b0c[2], w0tc[2], b1c[2], c0c[2];
#pragma unroll
  for (int nt = 0; nt < 2; ++nt) {
    const int col = cb + nt * 16 + cc;
    b0c[nt] = b0[col];
    w0tc[nt] = w0t[col];
    b1c[nt] = b1[col];
    c0c[nt] = c0[col];
  }

  // fragment-packed weight bases for this wave (c16 = 2w, 2w+1):
  const short* w1base = w1P + (size_t)(2 * w) * 4096 + lane * 8;
  const short* w20base = w20P + (size_t)(2 * w) * 4096 + lane * 8;

  // element (nt,q) of this thread's fragment: gbase + q*Hn + nt*16
  const size_t gbase = (size_t)(r0 + rq) * Hn + cb + cc;

  // persistent per-thread register state
  float z_[2][4], kzp[2][4], kza[2][4], hs[2][4], tr_[4];
  unsigned u_pk[2][2], g2_pk[2][2];  // bf16 pairs packed along q
#pragma unroll
  for (int nt = 0; nt < 2; ++nt) {
    const size_t i0 = gbase + nt * 16;
#pragma unroll
    for (int q = 0; q < 4; ++q) {
      z_[nt][q] = zg[i0 + (size_t)q * Hn];
      kzp[nt][q] = 0.f;
      hs[nt][q] = 0.f;
    }
    u_pk[nt][0] = pk2(u_g[i0], u_g[i0 + Hn]);
    u_pk[nt][1] = pk2(u_g[i0 + 2 * Hn], u_g[i0 + 3 * Hn]);
    g2_pk[nt][0] = pk2(g2_g[i0], g2_g[i0 + Hn]);
    g2_pk[nt][1] = pk2(g2_g[i0 + 2 * Hn], g2_g[i0 + 3 * Hn]);
  }
#pragma unroll
  for (int q = 0; q < 4; ++q) tr_[q] = 0.f;

  const f32x4 zero4 = {0.f, 0.f, 0.f, 0.f};

#pragma unroll 1
  for (int e = 0; e < 4 * NSTEPS; ++e) {
    const int j = e & 3, s = e >> 2;
    const float oj = (j == 0) ? 0.f : ((j == 3) ? 1.f : 0.5f);
    const float aj = (j == 0) ? 0.f : ((j == 3) ? DT : 0.5f * DT);
    const float mj = (j == 1 || j == 2) ? 2.f : 1.f;
    const float tval = ((float)s + oj) * DT;

    // ---- A: h0 = tanh(z + aj*kzp + b0 + t*w0t); m0 = (1-h0^2)*u -> stacked As
#pragma unroll
    for (int nt = 0; nt < 2; ++nt)
#pragma unroll
      for (int q = 0; q < 4; ++q) {
        const int row = rq + q;
        const int colh = cb + nt * 16 + cc;
        const float pre = z_[nt][q] + aj * kzp[nt][q] + b0c[nt] + tval * w0tc[nt];
        const float h = ftanh(pre);
        const float uq = (q & 1) ? upk_hi(u_pk[nt][q >> 1]) : upk_lo(u_pk[nt][q >> 1]);
        As[swz(row, colh)] = f2b(h);
        As[swz(16 + row, colh)] = f2b((1.f - h * h) * uq);
      }
    __syncthreads();

    // ---- B': [h0;m0] @ w1 (fragment-packed stream); epilogue: h1, trace, hs
    {
      f32x4 acc[2][2] = {{zero4, zero4}, {zero4, zero4}};  // [rb: h0/m0][nt]
#pragma unroll
      for (int ks = 0; ks < 8; ++ks) {
        const short8v b0v = *(const short8v*)(w1base + ks * 512);
        const short8v b1v = *(const short8v*)(w1base + 4096 + ks * 512);
        const short8v a0 = *(const short8v*)(As + swz(cc, g * 8 + ks * 32));
        const short8v a1 = *(const short8v*)(As + swz(16 + cc, g * 8 + ks * 32));
        acc[0][0] = __builtin_amdgcn_mfma_f32_16x16x32_bf16(a0, b0v, acc[0][0], 0, 0, 0);
        acc[0][1] = __builtin_amdgcn_mfma_f32_16x16x32_bf16(a0, b1v, acc[0][1], 0, 0, 0);
        acc[1][0] = __builtin_amdgcn_mfma_f32_16x16x32_bf16(a1, b0v, acc[1][0], 0, 0, 0);
        acc[1][1] = __builtin_amdgcn_mfma_f32_16x16x32_bf16(a1, b1v, acc[1][1], 0, 0, 0);
      }
#pragma unroll
      for (int nt = 0; nt < 2; ++nt)
#pragma unroll
        for (int q = 0; q < 4; ++q) {
          const float v = ftanh(acc[0][nt][q] + b1c[nt]);
          const float g2q =
              (q & 1) ? upk_hi(g2_pk[nt][q >> 1]) : upk_lo(g2_pk[nt][q >> 1]);
          tr_[q] += (DT6 * mj) * g2q * (1.f - v * v) * acc[1][nt][q];
          h1s[swz(rq + q, cb + nt * 16 + cc)] = f2b(v);
          hs[nt][q] += mj * v;
        }
    }
    __syncthreads();

    // ---- C: kz = h1@w20 + c0 ; RK4 state update (all registers)
    {
      f32x4 acc2[2] = {zero4, zero4};  // [nt]
#pragma unroll
      for (int ks = 0; ks < 8; ++ks) {
        const short8v b0v = *(const short8v*)(w20base + ks * 512);
        const short8v b1v = *(const short8v*)(w20base + 4096 + ks * 512);
        const short8v a = *(const short8v*)(h1s + swz(cc, g * 8 + ks * 32));
        acc2[0] = __builtin_amdgcn_mfma_f32_16x16x32_bf16(a, b0v, acc2[0], 0, 0, 0);
        acc2[1] = __builtin_amdgcn_mfma_f32_16x16x32_bf16(a, b1v, acc2[1], 0, 0, 0);
      }
#pragma unroll
      for (int nt = 0; nt < 2; ++nt)
#pragma unroll
        for (int q = 0; q < 4; ++q) {
          const float kzv = acc2[nt][q] + c0c[nt];
          if (j == 0) {
            kza[nt][q] = kzv;
            kzp[nt][q] = kzv;
          } else if (j < 3) {
            kza[nt][q] += mj * kzv;
            kzp[nt][q] = kzv;
          } else {
            z_[nt][q] += DT6 * (kza[nt][q] + kzv);
          }
        }
    }
    // no barrier: next A writes As only (disjoint from h1s); the A->B'
    // barrier orders h1s reuse across waves.
  }

  // ---- final: y = x + DT6 * HS@w2 + b2  (sum of dt*b2 over 8 steps = b2)
#pragma unroll
  for (int nt = 0; nt < 2; ++nt)
#pragma unroll
    for (int q = 0; q < 4; ++q)
      As[swz(rq + q, cb + nt * 16 + cc)] = f2b(hs[nt][q]);
  __syncthreads();
  {
    // 512 output cols over 8 waves -> wave covers 64 cols (c16 = 4w + nt)
    const short* w2base = w2P + (size_t)(4 * w) * 4096 + lane * 8;
    f32x4 facc[4] = {zero4, zero4, zero4, zero4};
#pragma unroll
    for (int ks = 0; ks < 8; ++ks) {
      const short8v a = *(const short8v*)(As + swz(cc, g * 8 + ks * 32));
#pragma unroll
      for (int nt = 0; nt < 4; ++nt) {
        const short8v bv = *(const short8v*)(w2base + nt * 4096 + ks * 512);
        facc[nt] = __builtin_amdgcn_mfma_f32_16x16x32_bf16(a, bv, facc[nt], 0, 0, 0);
      }
    }
#pragma unroll
    for (int nt = 0; nt < 4; ++nt) {
      const int colo = w * 64 + nt * 16 + cc;
      if (colo < Dn) {
        const float b2c = b2[colo];
#pragma unroll
        for (int q = 0; q < 4; ++q) {
          const size_t ix = (size_t)(r0 + rq + q) * Dn + colo;
          yout[ix] = x[ix] + DT6 * facc[nt][q] + b2c;
        }
      }
    }
  }

  // ---- trace reduction: over the 16 cc-lanes, then over 8 waves
#pragma unroll
  for (int q = 0; q < 4; ++q) {
    float v = tr_[q];
    v += __shfl_xor(v, 1);
    v += __shfl_xor(v, 2);
    v += __shfl_xor(v, 4);
    v += __shfl_xor(v, 8);
    if (cc == 0) red[rq + q][w] = v;
  }
  __syncthreads();
  if (tid < 16) {
    float t = 0.f;
#pragma unroll
    for (int ww = 0; ww < 8; ++ww) t += red[tid][ww];
    ldout[r0 + tid] = t;
  }
}

}  // namespace

extern "C" void kernel_launch(void* const* d_in, const int* in_sizes, int n_in,
                              void* d_out, int out_size, void* d_ws, size_t ws_size,
                              hipStream_t stream) {
  const float* x = (const float*)d_in[0];
  const float* cond = (const float*)d_in[1];
  const float* eps = (const float*)d_in[2];
  const float* w0 = (const float*)d_in[3];
  const float* b0 = (const float*)d_in[4];
  const float* w1 = (const float*)d_in[5];
  const float* b1 = (const float*)d_in[6];
  const float* w2 = (const float*)d_in[7];
  const float* b2 = (const float*)d_in[8];
  const float* w0c = w0 + (size_t)508 * Hn;  // cond row
  const float* w0t = w0 + (size_t)509 * Hn;  // time row

  const size_t BD = (size_t)Bn * Dn, BH = (size_t)Bn * Hn;
  char* p = (char*)d_ws;
  auto alloc_f = [&](size_t n) { float* r = (float*)p; p += n * 4; return r; };
  auto alloc_s = [&](size_t n) { short* r = (short*)p; p += ((n * 2 + 15) & ~15ull); return r; };

  float* zg = alloc_f(BH);
  float* c0 = alloc_f(256);
  short* u_g = alloc_s(BH);
  short* g2_g = alloc_s(BH);
  short* w0T = alloc_s(256 * 512);
  short* w1T = alloc_s(256 * 256);
  short* w2b = alloc_s(256 * 512);
  short* w2T = alloc_s(512 * 256);
  short* w20T = alloc_s(256 * 256);
  short* w1P = alloc_s(256 * 256);   // fragment-packed
  short* w20P = alloc_s(256 * 256);  // fragment-packed
  short* w2P = alloc_s(512 * 256);   // fragment-packed

  float* yout = (float*)d_out;        // [B, D]
  float* ldout = (float*)d_out + BD;  // [B]

  const dim3 blk(256);
  const dim3 gH(Hn / 64, Bn / 64);  // (4,128)
  const dim3 gW(4, 4);

  // ---- setup (weights + z/u/g2 precompute; x/eps casts folded into GEMMs)
  k_cast_bf<<<512, blk, 0, stream>>>(w2, Hn, Dn, w2b, Kp);
  k_transpose_bf<<<256, blk, 0, stream>>>(w1, Hn, Hn, w1T, Hn, Hn);
  k_transpose_bf<<<512, blk, 0, stream>>>(w0, Dn, Hn, w0T, Hn, Kp);
  k_transpose_bf<<<512, blk, 0, stream>>>(w2, Hn, Dn, w2T, Kp, Hn);
  k_c0<<<1, blk, 0, stream>>>(w0, b2, c0);
  k_w20t<<<gW, blk, 0, stream>>>(w0T, w2b, w20T);
  k_ginitx<<<gH, blk, 0, stream>>>(x, w0T, cond, w0c, zg);
  k_giniteps<<<gH, blk, 0, stream>>>(eps, w0T, w2b, u_g, g2_g);
  k_fragpack<<<256, blk, 0, stream>>>(w1T, w1P, 256 * 256);
  k_fragpack<<<256, blk, 0, stream>>>(w20T, w20P, 256 * 256);
  k_fragpack<<<512, blk, 0, stream>>>(w2T, w2P, 512 * 256);

  // ---- the whole ODE in one kernel ----
  k_mega<<<dim3(Bn / 16), dim3(512), 0, stream>>>(zg, u_g, g2_g, w1P, w20P,
                                                  w2P, b0, w0t, b1, c0, b2, x,
                                                  yout, ldout);
}